// Round 2
// baseline (544.476 us; speedup 1.0000x reference)
//
#include <hip/hip_runtime.h>

// LSTM cell fused as one GEMM: Z[B,2048] = [input|h0] (bf16) @ Wint^T (bf16)
// Wint column order c: h_group = c>>6, gate = (c>>4)&3, h_low = c&15
//   => each wave's four 16-col MFMA subtiles are gates i,f,o,g at the SAME h,
//      so the gate nonlinearity fuses into the epilogue lane-locally.
// Pipeline (T3/T4-lite): double-buffered LDS, ONE raw s_barrier per K-step,
// counted s_waitcnt vmcnt(4) so the next-next A fp32 prefetch stays in flight
// across the barrier (a __syncthreads would drain it - that was round 1's bug).
// A: fp32 global -> regs -> cvt -> ds_write (XOR-swizzled);
// B: global_load_lds, linear dest + pre-swizzled SOURCE column (rule #21).
// T1: XCD-chunked block swizzle so the 16 bn-blocks sharing an A-panel land
// on one XCD's L2 (4096 % 8 == 0 -> bijective).
// B=32768, E=H=512, K=E+H=1024, N=4H=2048.

#define BQ 32768
#define HQ 512
#define KK 1024
#define BH (32768 * 512)  // 16777216 elements per output

typedef __bf16 bf16x8 __attribute__((ext_vector_type(8)));
typedef float f32x4 __attribute__((ext_vector_type(4)));

__device__ __forceinline__ unsigned short f2bf(float f) {
    unsigned int u = __float_as_uint(f);
    unsigned int r = (u + 0x7fffu + ((u >> 16) & 1u)) >> 16;
    return (unsigned short)r;
}

__device__ __forceinline__ void gld_lds16(const unsigned short* g, unsigned short* l) {
    __builtin_amdgcn_global_load_lds(
        (const __attribute__((address_space(1))) void*)g,
        (__attribute__((address_space(3))) void*)l,
        16, 0, 0);
}

__device__ __forceinline__ bf16x8 cvt8(f32x4 a, f32x4 b) {
    bf16x8 w;
    w[0] = (__bf16)a[0]; w[1] = (__bf16)a[1]; w[2] = (__bf16)a[2]; w[3] = (__bf16)a[3];
    w[4] = (__bf16)b[0]; w[5] = (__bf16)b[1]; w[6] = (__bf16)b[2]; w[7] = (__bf16)b[3];
    return w;
}

struct AR { f32x4 a, b, c, d; };

__device__ __forceinline__ void loadA(const float* gAx, const float* gAh, int kt, AR& s) {
    const float* p = (kt < 512) ? (gAx + kt) : (gAh + (kt - 512));
    s.a = *(const f32x4*)(p + 0);
    s.b = *(const f32x4*)(p + 4);
    s.c = *(const f32x4*)(p + 8);
    s.d = *(const f32x4*)(p + 12);
}

// ---- prepass: weight packing only (8 MiB read, trivial) --------------------

__global__ __launch_bounds__(256) void pack_W(const float* __restrict__ Wx,
                                              const float* __restrict__ Wh,
                                              const float* __restrict__ bx,
                                              const float* __restrict__ bh,
                                              unsigned short* __restrict__ Wint,
                                              float* __restrict__ biasc) {
    int j = blockIdx.x * 256 + threadIdx.x;  // 2048 rows * 256 quads
    int c = j >> 8;
    int kc = (j & 255) * 4;
    int gate = (c >> 4) & 3;
    int h = ((c >> 6) << 4) + (c & 15);
    const float* src = (kc < 512)
        ? (Wx + ((size_t)gate * 512 + h) * 512 + kc)
        : (Wh + ((size_t)gate * 512 + h) * 512 + (kc - 512));
    float4 v = *(const float4*)src;
    ushort4 o;
    o.x = f2bf(v.x); o.y = f2bf(v.y); o.z = f2bf(v.z); o.w = f2bf(v.w);
    *(ushort4*)&Wint[(size_t)c * 1024 + kc] = o;
    if ((j & 255) == 0) biasc[c] = bx[gate * 512 + h] + bh[gate * 512 + h];
}

// ---- fused GEMM + LSTM epilogue --------------------------------------------
// 128x128 tile, BK=32, 4 waves in 2x2; wave tile 64x64 = 4x4 MFMA 16x16x32.

__global__ __launch_bounds__(256, 4) void lstm_gemm(const float* __restrict__ xin,
                                                    const float* __restrict__ hin,
                                                    const unsigned short* __restrict__ Wint,
                                                    const float* __restrict__ biasc,
                                                    const float* __restrict__ c0,
                                                    float* __restrict__ out) {
    __shared__ __align__(16) unsigned short ldsA[2][128 * 32];
    __shared__ __align__(16) unsigned short ldsB[2][128 * 32];

    const int tid = threadIdx.x;
    const int lane = tid & 63;
    const int wave = tid >> 6;
    const int wm = wave >> 1;   // 0..1 (row of wave grid)
    const int wn = wave & 1;    // 0..1 (col of wave grid)
    const int quad = lane >> 4; // 0..3
    const int lrow = lane & 15; // 0..15

    // XCD-chunked swizzle: xcd = bid&7 gets bm in [xcd*32, xcd*32+32), all bn.
    const int bid = blockIdx.x;
    const int l = bid >> 3;
    const int bm = (bid & 7) * 32 + (l >> 4);  // 0..255
    const int bn = l & 15;                     // 0..15
    const int m0 = bm * 128;
    const int n0 = bn * 128;

    // ---- A staging: thread t owns row tid>>1, 16-float half tid&1 of the
    //      32-col K-tile. fp32 load -> cvt -> ds_write_b128, XOR-swizzled.
    const int arow = tid >> 1;          // 0..127
    const int ahalf = tid & 1;
    const int aswz = (arow >> 1) & 3;
    const float* gAx = xin + (size_t)(m0 + arow) * HQ + ahalf * 16;
    const float* gAh = hin + (size_t)(m0 + arow) * HQ + ahalf * 16;
    const int wa0 = arow * 32 + (((ahalf * 2 + 0) ^ aswz) * 8);
    const int wa1 = arow * 32 + (((ahalf * 2 + 1) ^ aswz) * 8);

    // ---- B staging: global_load_lds, linear LDS dest (tid*16B), source
    //      column 16B-unit pre-swizzled so LDS holds unit g at slot g^((row>>1)&3).
    const int brow = tid >> 2;          // 0..63
    const int bunit = (tid & 3) ^ ((tid >> 3) & 3);
    const unsigned short* gB = Wint + (size_t)(n0 + brow) * KK + bunit * 8;

    // ---- fragment read offset: LDS unit quad^((row>>1)&3) holds global unit quad
    const int koff = (quad ^ ((lrow >> 1) & 3)) * 8;

    f32x4 acc[4][4];
    for (int i = 0; i < 4; i++)
        for (int j = 0; j < 4; j++) {
            f32x4 z = {0.f, 0.f, 0.f, 0.f};
            acc[i][j] = z;
        }

    AR s0, s1;

    // ---- prologue: tile0 staged to buf0; tile1 A-regs in flight
    loadA(gAx, gAh, 0, s0);                         // vm q: [A0 x4]
    gld_lds16(gB, &ldsB[0][tid * 8]);               // vm q: [A0 x4, B0 x2]
    gld_lds16(gB + (size_t)64 * KK, &ldsB[0][2048 + tid * 8]);
    *(bf16x8*)&ldsA[0][wa0] = cvt8(s0.a, s0.b);     // compiler waits A0 (drains B0 too)
    *(bf16x8*)&ldsA[0][wa1] = cvt8(s0.c, s0.d);
    loadA(gAx, gAh, 32, s1);                        // vm q: [A1 x4]
    asm volatile("s_waitcnt vmcnt(4) lgkmcnt(0)" ::: "memory");
    __builtin_amdgcn_s_barrier();

// One K-step: read tile I from buf[CUR]; stage tile I+1 (B via gld_lds,
// A via cvt+ds_write of WREG) into buf[CUR^1]; issue A(I+2) loads into LREG.
// Pre-barrier wait: vmcnt(4) keeps the 4 A(I+2) loads in flight (in-order
// count: the 2 older gld_lds B(I+1) ops are what gets waited on).
#define STEP(I, CUR, WREG, LREG) do {                                          \
    const int ktn_ = ((I) + 1) * 32;                                           \
    gld_lds16(gB + ktn_, &ldsB[(CUR) ^ 1][tid * 8]);                           \
    gld_lds16(gB + (size_t)64 * KK + ktn_, &ldsB[(CUR) ^ 1][2048 + tid * 8]);  \
    bf16x8 af[4], bfr[4];                                                      \
    for (int mi = 0; mi < 4; mi++)                                             \
        af[mi] = *(const bf16x8*)&ldsA[CUR][(wm * 64 + mi * 16 + lrow) * 32 + koff]; \
    for (int ni = 0; ni < 4; ni++)                                             \
        bfr[ni] = *(const bf16x8*)&ldsB[CUR][(wn * 64 + ni * 16 + lrow) * 32 + koff]; \
    *(bf16x8*)&ldsA[(CUR) ^ 1][wa0] = cvt8(WREG.a, WREG.b);                    \
    *(bf16x8*)&ldsA[(CUR) ^ 1][wa1] = cvt8(WREG.c, WREG.d);                    \
    int kt2_ = ((I) + 2) * 32;                                                 \
    if (kt2_ >= KK) kt2_ = KK - 32;                                            \
    loadA(gAx, gAh, kt2_, LREG);                                               \
    for (int mi = 0; mi < 4; mi++)                                             \
        for (int ni = 0; ni < 4; ni++)                                         \
            acc[mi][ni] = __builtin_amdgcn_mfma_f32_16x16x32_bf16(             \
                af[mi], bfr[ni], acc[mi][ni], 0, 0, 0);                        \
    asm volatile("s_waitcnt vmcnt(4) lgkmcnt(0)" ::: "memory");                \
    __builtin_amdgcn_s_barrier();                                              \
} while (0)

    for (int ii = 0; ii < 15; ++ii) {
        STEP(2 * ii + 0, 0, s1, s0);
        STEP(2 * ii + 1, 1, s0, s1);
    }
    STEP(30, 0, s1, s0);
#undef STEP

    // last tile (i=31) from buf[1]: compute only, no staging, no barrier
    {
        bf16x8 af[4], bfr[4];
        for (int mi = 0; mi < 4; mi++)
            af[mi] = *(const bf16x8*)&ldsA[1][(wm * 64 + mi * 16 + lrow) * 32 + koff];
        for (int ni = 0; ni < 4; ni++)
            bfr[ni] = *(const bf16x8*)&ldsB[1][(wn * 64 + ni * 16 + lrow) * 32 + koff];
        for (int mi = 0; mi < 4; mi++)
            for (int ni = 0; ni < 4; ni++)
                acc[mi][ni] = __builtin_amdgcn_mfma_f32_16x16x32_bf16(
                    af[mi], bfr[ni], acc[mi][ni], 0, 0, 0);
    }

    // epilogue: lane owns gates i,f,o,g (ni=0..3) at h fixed per lane
    float bi[4];
    for (int ni = 0; ni < 4; ni++)
        bi[ni] = biasc[n0 + wn * 64 + ni * 16 + lrow];
    const int h = (bn * 2 + wn) * 16 + lrow;

    for (int mi = 0; mi < 4; mi++) {
        for (int r = 0; r < 4; r++) {
            int b = m0 + wm * 64 + mi * 16 + quad * 4 + r;
            float zi = acc[mi][0][r] + bi[0];
            float zf = acc[mi][1][r] + bi[1];
            float zo = acc[mi][2][r] + bi[2];
            float zg = acc[mi][3][r] + bi[3];
            float ig = 1.f / (1.f + __expf(-zi));
            float fg = 1.f / (1.f + __expf(-zf));
            float og = 1.f / (1.f + __expf(-zo));
            float gg = 1.f - 2.f / (__expf(2.f * zg) + 1.f);  // tanh, stable both ends
            float c0v = c0[(size_t)b * HQ + h];
            float c1 = fg * c0v + ig * gg;
            float th = 1.f - 2.f / (__expf(2.f * c1) + 1.f);
            out[(size_t)b * HQ + h] = og * th;                 // h1
            out[(size_t)BH + (size_t)b * HQ + h] = c1;         // c1
        }
    }
}

extern "C" void kernel_launch(void* const* d_in, const int* in_sizes, int n_in,
                              void* d_out, int out_size, void* d_ws, size_t ws_size,
                              hipStream_t stream) {
    (void)in_sizes; (void)n_in; (void)out_size; (void)ws_size;
    const float* input = (const float*)d_in[0];
    const float* h0    = (const float*)d_in[1];
    const float* c0    = (const float*)d_in[2];
    const float* Wx    = (const float*)d_in[3];
    const float* bx    = (const float*)d_in[4];
    const float* Wh    = (const float*)d_in[5];
    const float* bh    = (const float*)d_in[6];
    float* out = (float*)d_out;

    char* ws = (char*)d_ws;
    unsigned short* Wint = (unsigned short*)ws;                      // 4 MiB
    float* biasc = (float*)(ws + (size_t)4 * 1024 * 1024);           // 8 KiB

    pack_W<<<2048, 256, 0, stream>>>(Wx, Wh, bx, bh, Wint, biasc);
    lstm_gemm<<<4096, 256, 0, stream>>>(input, h0, Wint, biasc, c0, out);
}

// Round 3
// 476.421 us; speedup vs baseline: 1.1428x; 1.1428x over previous
//
#include <hip/hip_runtime.h>

// LSTM cell fused as one GEMM: Z[B,2048] = [input|h0] (bf16) @ Wint^T (bf16)
// Wint column order c: h_group = c>>6, gate = (c>>4)&3, h_low = c&15
//   => each wave's four 16-col MFMA subtiles are gates i,f,o,g at the SAME h,
//      so the gate nonlinearity fuses into the epilogue lane-locally.
//
// GEMM structure: 8-phase-style deep pipeline (T3+T4+T5 per catalog):
//   BM=256 x BN=128, BK=64, 512 threads = 8 waves (4M x 2N), per-wave 64x64.
//   LDS: 3 buffers (A 16K + B 8K each pair... A[3][2][256x32], B[3][2][128x32]
//   = 144 KiB). Stage lead = 2 K-tiles: while computing T (buf T%3), stage
//   T+2 into (T+2)%3 -> reader/pending/writer bufs always distinct (race-free).
//   ONE s_waitcnt vmcnt(6) per K-tile (6 = T+2's in-flight gld_lds); never 0
//   in steady state. setprio(1) around each 16-MFMA cluster.
//   Both operands staged via global_load_lds (linear dest) with pre-swizzled
//   SOURCE column unit ((t&3)^((t>>3)&3)) and matching read-side
//   koff = (quad^((lrow>>1)&3))*8 -- measured 0 bank conflicts in r1/r2.
// B=32768, E=H=512, K=E+H=1024, N=4H=2048.

#define BQ 32768
#define HQ 512
#define KK 1024
#define BH (32768 * 512)  // elements per output

typedef __bf16 bf16x8 __attribute__((ext_vector_type(8)));
typedef float f32x4 __attribute__((ext_vector_type(4)));

__device__ __forceinline__ unsigned short f2bf(float f) {
    unsigned int u = __float_as_uint(f);
    unsigned int r = (u + 0x7fffu + ((u >> 16) & 1u)) >> 16;
    return (unsigned short)r;
}

__device__ __forceinline__ void gld_lds16(const unsigned short* g, unsigned short* l) {
    __builtin_amdgcn_global_load_lds(
        (const __attribute__((address_space(1))) void*)g,
        (__attribute__((address_space(3))) void*)l,
        16, 0, 0);
}

// ---- prepass: fp32 -> bf16 packing -----------------------------------------

__global__ __launch_bounds__(256) void pack_X(const float* __restrict__ in,
                                              const float* __restrict__ h0,
                                              unsigned short* __restrict__ Xcat) {
    const int NQ = BQ * HQ / 4;  // 4194304 quads per source
    int gi = blockIdx.x * 256 + threadIdx.x;
    const float* src;
    size_t dst;
    if (gi < NQ) {
        int e = gi * 4;
        int b = e >> 9, col = e & 511;
        src = in + e;
        dst = (size_t)b * 1024 + col;
    } else {
        int e = (gi - NQ) * 4;
        int b = e >> 9, col = e & 511;
        src = h0 + e;
        dst = (size_t)b * 1024 + 512 + col;
    }
    float4 v = *(const float4*)src;
    ushort4 o;
    o.x = f2bf(v.x); o.y = f2bf(v.y); o.z = f2bf(v.z); o.w = f2bf(v.w);
    *(ushort4*)&Xcat[dst] = o;
}

__global__ __launch_bounds__(256) void pack_W(const float* __restrict__ Wx,
                                              const float* __restrict__ Wh,
                                              const float* __restrict__ bx,
                                              const float* __restrict__ bh,
                                              unsigned short* __restrict__ Wint,
                                              float* __restrict__ biasc) {
    int j = blockIdx.x * 256 + threadIdx.x;  // 2048 rows * 256 quads
    int c = j >> 8;
    int kc = (j & 255) * 4;
    int gate = (c >> 4) & 3;
    int h = ((c >> 6) << 4) + (c & 15);
    const float* src = (kc < 512)
        ? (Wx + ((size_t)gate * 512 + h) * 512 + kc)
        : (Wh + ((size_t)gate * 512 + h) * 512 + (kc - 512));
    float4 v = *(const float4*)src;
    ushort4 o;
    o.x = f2bf(v.x); o.y = f2bf(v.y); o.z = f2bf(v.z); o.w = f2bf(v.w);
    *(ushort4*)&Wint[(size_t)c * 1024 + kc] = o;
    if ((j & 255) == 0) biasc[c] = bx[gate * 512 + h] + bh[gate * 512 + h];
}

// ---- fused GEMM + LSTM epilogue --------------------------------------------

__global__ __launch_bounds__(512, 2) void lstm_gemm(const unsigned short* __restrict__ Xcat,
                                                    const unsigned short* __restrict__ Wint,
                                                    const float* __restrict__ biasc,
                                                    const float* __restrict__ c0,
                                                    float* __restrict__ out) {
    // [buf][ksub][row*32 + unit*8] ; A rows 256, B rows 128; row = 64B
    __shared__ __align__(16) unsigned short ldsA[3][2][256 * 32];  // 96 KiB
    __shared__ __align__(16) unsigned short ldsB[3][2][128 * 32];  // 48 KiB

    const int tid = threadIdx.x;
    const int lane = tid & 63;
    const int wave = tid >> 6;     // 0..7
    const int wm = wave >> 1;      // 0..3 (M)
    const int wn = wave & 1;       // 0..1 (N)
    const int quad = lane >> 4;    // 0..3
    const int lrow = lane & 15;    // 0..15

    // XCD-chunked swizzle (2048 % 8 == 0 -> bijective):
    // xcd = bid&7 owns bm in [xcd*16, xcd*16+16), all 16 bn.
    const int bid = blockIdx.x;
    const int l = bid >> 3;
    const int bm = (bid & 7) * 16 + (l >> 4);  // 0..127
    const int bn = l & 15;                     // 0..15
    const int m0 = bm * 256;
    const int n0 = bn * 128;

    // staging: thread t = one 16B quantum; row t>>2, source unit swizzled
    const int trow = tid >> 2;                                   // 0..127
    const int aunit = ((tid & 3) ^ ((tid >> 3) & 3)) * 8;        // src col unit
    const int t8 = tid * 8;                                      // LDS elem offset
    const unsigned short* gA0 = Xcat + (size_t)(m0 + trow) * KK + aunit;
    const unsigned short* gA1 = gA0 + (size_t)128 * KK;          // rows 128..255
    const unsigned short* gB0 = Wint + (size_t)(n0 + trow) * KK + aunit;

    // read-side swizzle (inverse of source swizzle; measured 0 conflicts)
    const int koff = (quad ^ ((lrow >> 1) & 3)) * 8;

    f32x4 acc[4][4];
#pragma unroll
    for (int i = 0; i < 4; i++)
#pragma unroll
        for (int j = 0; j < 4; j++) {
            f32x4 z = {0.f, 0.f, 0.f, 0.f};
            acc[i][j] = z;
        }

    // ---- prologue: fully stage tiles 0 (buf0) and 1 (buf1); 12 loads/thread
#pragma unroll
    for (int tt = 0; tt < 2; ++tt) {
        const int kt = tt * 64;
        gld_lds16(gA0 + kt,      &ldsA[tt][0][t8]);
        gld_lds16(gA1 + kt,      &ldsA[tt][0][4096 + t8]);
        gld_lds16(gB0 + kt,      &ldsB[tt][0][t8]);
        gld_lds16(gA0 + kt + 32, &ldsA[tt][1][t8]);
        gld_lds16(gA1 + kt + 32, &ldsA[tt][1][4096 + t8]);
        gld_lds16(gB0 + kt + 32, &ldsB[tt][1][t8]);
    }
    asm volatile("s_waitcnt vmcnt(6)" ::: "memory");  // tile0 landed; tile1 in flight
    __builtin_amdgcn_s_barrier();

    int bufR = 0;  // = T % 3
    int bufS = 2;  // = (T+2) % 3

    for (int T = 0; T < 16; ++T) {
        const int kt2 = T * 64 + 128;  // K-offset of tile T+2
        const bool st = (T < 14);

        // ---------------- phase 0 (ksub = 0) ----------------
        {
            bf16x8 af[4], bfr[4];
#pragma unroll
            for (int mi = 0; mi < 4; mi++)
                af[mi] = *(const bf16x8*)&ldsA[bufR][0][(wm * 64 + mi * 16 + lrow) * 32 + koff];
#pragma unroll
            for (int ni = 0; ni < 4; ni++)
                bfr[ni] = *(const bf16x8*)&ldsB[bufR][0][(wn * 64 + ni * 16 + lrow) * 32 + koff];
            if (st) {
                gld_lds16(gA0 + kt2, &ldsA[bufS][0][t8]);
                gld_lds16(gA1 + kt2, &ldsA[bufS][0][4096 + t8]);
                gld_lds16(gB0 + kt2, &ldsB[bufS][0][t8]);
            }
            __builtin_amdgcn_s_barrier();
            __builtin_amdgcn_s_setprio(1);
#pragma unroll
            for (int mi = 0; mi < 4; mi++)
#pragma unroll
                for (int ni = 0; ni < 4; ni++)
                    acc[mi][ni] = __builtin_amdgcn_mfma_f32_16x16x32_bf16(
                        af[mi], bfr[ni], acc[mi][ni], 0, 0, 0);
            __builtin_amdgcn_s_setprio(0);
            __builtin_amdgcn_s_barrier();
        }

        // ---------------- phase 1 (ksub = 1) ----------------
        {
            bf16x8 af[4], bfr[4];
#pragma unroll
            for (int mi = 0; mi < 4; mi++)
                af[mi] = *(const bf16x8*)&ldsA[bufR][1][(wm * 64 + mi * 16 + lrow) * 32 + koff];
#pragma unroll
            for (int ni = 0; ni < 4; ni++)
                bfr[ni] = *(const bf16x8*)&ldsB[bufR][1][(wn * 64 + ni * 16 + lrow) * 32 + koff];
            if (st) {
                gld_lds16(gA0 + kt2 + 32, &ldsA[bufS][1][t8]);
                gld_lds16(gA1 + kt2 + 32, &ldsA[bufS][1][4096 + t8]);
                gld_lds16(gB0 + kt2 + 32, &ldsB[bufS][1][t8]);
                // tile T+1 fully landed; tile T+2's 6 loads stay in flight
                asm volatile("s_waitcnt vmcnt(6)" ::: "memory");
            } else {
                asm volatile("s_waitcnt vmcnt(0)" ::: "memory");  // tail drain
            }
            __builtin_amdgcn_s_barrier();
            __builtin_amdgcn_s_setprio(1);
#pragma unroll
            for (int mi = 0; mi < 4; mi++)
#pragma unroll
                for (int ni = 0; ni < 4; ni++)
                    acc[mi][ni] = __builtin_amdgcn_mfma_f32_16x16x32_bf16(
                        af[mi], bfr[ni], acc[mi][ni], 0, 0, 0);
            __builtin_amdgcn_s_setprio(0);
            __builtin_amdgcn_s_barrier();
        }

        bufR = (bufR == 2) ? 0 : bufR + 1;
        bufS = (bufS == 2) ? 0 : bufS + 1;
    }

    // epilogue: lane owns gates i,f,o,g (ni=0..3) at h fixed per lane
    float bi[4];
#pragma unroll
    for (int ni = 0; ni < 4; ni++)
        bi[ni] = biasc[n0 + wn * 64 + ni * 16 + lrow];
    const int h = (bn * 2 + wn) * 16 + lrow;

#pragma unroll
    for (int mi = 0; mi < 4; mi++) {
#pragma unroll
        for (int r = 0; r < 4; r++) {
            int b = m0 + wm * 64 + mi * 16 + quad * 4 + r;
            float zi = acc[mi][0][r] + bi[0];
            float zf = acc[mi][1][r] + bi[1];
            float zo = acc[mi][2][r] + bi[2];
            float zg = acc[mi][3][r] + bi[3];
            float ig = 1.f / (1.f + __expf(-zi));
            float fg = 1.f / (1.f + __expf(-zf));
            float og = 1.f / (1.f + __expf(-zo));
            float gg = 1.f - 2.f / (__expf(2.f * zg) + 1.f);  // tanh, stable both ends
            float c0v = c0[(size_t)b * HQ + h];
            float c1 = fg * c0v + ig * gg;
            float th = 1.f - 2.f / (__expf(2.f * c1) + 1.f);
            out[(size_t)b * HQ + h] = og * th;                 // h1
            out[(size_t)BH + (size_t)b * HQ + h] = c1;         // c1
        }
    }
}

extern "C" void kernel_launch(void* const* d_in, const int* in_sizes, int n_in,
                              void* d_out, int out_size, void* d_ws, size_t ws_size,
                              hipStream_t stream) {
    (void)in_sizes; (void)n_in; (void)out_size; (void)ws_size;
    const float* input = (const float*)d_in[0];
    const float* h0    = (const float*)d_in[1];
    const float* c0    = (const float*)d_in[2];
    const float* Wx    = (const float*)d_in[3];
    const float* bx    = (const float*)d_in[4];
    const float* Wh    = (const float*)d_in[5];
    const float* bh    = (const float*)d_in[6];
    float* out = (float*)d_out;

    char* ws = (char*)d_ws;
    unsigned short* Xcat = (unsigned short*)ws;                      // 64 MiB
    unsigned short* Wint = (unsigned short*)(ws + (size_t)67108864); // 4 MiB
    float* biasc = (float*)(ws + (size_t)71303168);                  // 8 KiB

    pack_X<<<32768, 256, 0, stream>>>(input, h0, Xcat);
    pack_W<<<2048, 256, 0, stream>>>(Wx, Wh, bx, bh, Wint, biasc);
    lstm_gemm<<<2048, 512, 0, stream>>>(Xcat, Wint, biasc, c0, out);
}

// Round 4
// 427.523 us; speedup vs baseline: 1.2736x; 1.1144x over previous
//
#include <hip/hip_runtime.h>

// LSTM cell fused as one GEMM: Z[B,2048] = [input|h0] (bf16) @ Wint^T (bf16)
// Wint column order c: h_group = c>>6, gate = (c>>4)&3, h_low = c&15
//   => each wave's four 16-col MFMA subtiles are gates i,f,o,g at the SAME h,
//      so the gate nonlinearity fuses into the epilogue lane-locally.
//
// m201-geometry port: BM=BN=256, BK=64, 512 thr = 8 waves (2M x 4N),
// per-wave 128x64 (acc[8][4]). LDS = 2 x (A 32K + B 32K) = 128 KiB.
// Per K-tile: stage A(next) at entry + vmcnt(4) (counted: leaves next A in
// flight, lands current tile), stage B(next) mid-tile; 4 setprio'd 16-MFMA
// clusters; operand-hold gives 24 ds_read_b128 per 64 MFMA per wave.
// Swizzle: source unit (t&7)^(row&7) with read unit (ks*4+quad)^(lrow&7)
// (involution, <=2-way within quad-phase).
// B=32768, E=H=512, K=1024, N=2048.

#define BQ 32768
#define HQ 512
#define KK 1024
#define BH (32768 * 512)  // elements per output

typedef __bf16 bf16x8 __attribute__((ext_vector_type(8)));
typedef float f32x4 __attribute__((ext_vector_type(4)));

__device__ __forceinline__ unsigned short f2bf(float f) {
    unsigned int u = __float_as_uint(f);
    unsigned int r = (u + 0x7fffu + ((u >> 16) & 1u)) >> 16;
    return (unsigned short)r;
}

__device__ __forceinline__ void gld_lds16(const unsigned short* g, unsigned short* l) {
    __builtin_amdgcn_global_load_lds(
        (const __attribute__((address_space(1))) void*)g,
        (__attribute__((address_space(3))) void*)l,
        16, 0, 0);
}

// ---- prepass: fp32 -> bf16 packing -----------------------------------------

__global__ __launch_bounds__(256) void pack_X(const float* __restrict__ in,
                                              const float* __restrict__ h0,
                                              unsigned short* __restrict__ Xcat) {
    const int NQ = BQ * HQ / 4;
    int gi = blockIdx.x * 256 + threadIdx.x;
    const float* src;
    size_t dst;
    if (gi < NQ) {
        int e = gi * 4;
        int b = e >> 9, col = e & 511;
        src = in + e;
        dst = (size_t)b * 1024 + col;
    } else {
        int e = (gi - NQ) * 4;
        int b = e >> 9, col = e & 511;
        src = h0 + e;
        dst = (size_t)b * 1024 + 512 + col;
    }
    float4 v = *(const float4*)src;
    ushort4 o;
    o.x = f2bf(v.x); o.y = f2bf(v.y); o.z = f2bf(v.z); o.w = f2bf(v.w);
    *(ushort4*)&Xcat[dst] = o;
}

__global__ __launch_bounds__(256) void pack_W(const float* __restrict__ Wx,
                                              const float* __restrict__ Wh,
                                              const float* __restrict__ bx,
                                              const float* __restrict__ bh,
                                              unsigned short* __restrict__ Wint,
                                              float* __restrict__ biasc) {
    int j = blockIdx.x * 256 + threadIdx.x;
    int c = j >> 8;
    int kc = (j & 255) * 4;
    int gate = (c >> 4) & 3;
    int h = ((c >> 6) << 4) + (c & 15);
    const float* src = (kc < 512)
        ? (Wx + ((size_t)gate * 512 + h) * 512 + kc)
        : (Wh + ((size_t)gate * 512 + h) * 512 + (kc - 512));
    float4 v = *(const float4*)src;
    ushort4 o;
    o.x = f2bf(v.x); o.y = f2bf(v.y); o.z = f2bf(v.z); o.w = f2bf(v.w);
    *(ushort4*)&Wint[(size_t)c * 1024 + kc] = o;
    if ((j & 255) == 0) biasc[c] = bx[gate * 512 + h] + bh[gate * 512 + h];
}

// ---- fused GEMM + LSTM epilogue --------------------------------------------

__global__ __launch_bounds__(512, 2) void lstm_gemm(const unsigned short* __restrict__ Xcat,
                                                    const unsigned short* __restrict__ Wint,
                                                    const float* __restrict__ biasc,
                                                    const float* __restrict__ c0,
                                                    float* __restrict__ out) {
    __shared__ __align__(16) unsigned short ldsA[2][256 * 64];  // 64 KiB
    __shared__ __align__(16) unsigned short ldsB[2][256 * 64];  // 64 KiB

    const int tid = threadIdx.x;
    const int lane = tid & 63;
    const int wave = tid >> 6;     // 0..7
    const int wm = wave >> 2;      // 0..1 (M)
    const int wn = wave & 3;       // 0..3 (N) = h_group within block
    const int quad = lane >> 4;    // 0..3
    const int lrow = lane & 15;    // 0..15

    // XCD-chunked swizzle (1024 % 8 == 0 -> bijective): xcd owns 16 bm x 8 bn.
    const int bid = blockIdx.x;
    const int l = bid >> 3;
    const int bm = (bid & 7) * 16 + (l >> 3);  // 0..127
    const int bn = l & 7;                      // 0..7
    const int m0 = bm * 256;
    const int n0 = bn * 256;

    // staging: thread t covers (row = q*64 + (t>>3), unit (t&7)), unit source-
    // swizzled by row&7 ( == (t>>3)&7 since q*64 % 8 == 0 ).
    const int srow = tid >> 3;                        // 0..63
    const int scol = ((tid & 7) ^ (srow & 7)) * 8;    // swizzled src col (elems)
    const unsigned short* pA = Xcat + (size_t)(m0 + srow) * KK + scol;
    const unsigned short* pB = Wint + (size_t)(n0 + srow) * KK + scol;

    // read-side: unit (ks*4+quad) ^ (lrow&7); row stride 64 elems (128 B)
    const int ro = lrow * 64;
    const int u0 = ((quad)     ^ (lrow & 7)) * 8;
    const int u1 = ((quad + 4) ^ (lrow & 7)) * 8;
    const int ab = (wm * 128) * 64 + ro;   // + (mh*64 + mi*16)*64 + u
    const int bb = (wn * 64) * 64 + ro;    // + (g*16)*64 + u

    f32x4 acc[8][4];
#pragma unroll
    for (int i = 0; i < 8; i++)
#pragma unroll
        for (int j = 0; j < 4; j++) {
            f32x4 z = {0.f, 0.f, 0.f, 0.f};
            acc[i][j] = z;
        }

#define STAGE_A(Tt, nb) do { const size_t ko_ = (size_t)(Tt) * 64;             \
    gld_lds16(pA + ko_,                       &ldsA[nb][(0 * 512 + tid) * 8]); \
    gld_lds16(pA + 64 * (size_t)KK + ko_,     &ldsA[nb][(1 * 512 + tid) * 8]); \
    gld_lds16(pA + 128 * (size_t)KK + ko_,    &ldsA[nb][(2 * 512 + tid) * 8]); \
    gld_lds16(pA + 192 * (size_t)KK + ko_,    &ldsA[nb][(3 * 512 + tid) * 8]); \
} while (0)
#define STAGE_B(Tt, nb) do { const size_t ko_ = (size_t)(Tt) * 64;             \
    gld_lds16(pB + ko_,                       &ldsB[nb][(0 * 512 + tid) * 8]); \
    gld_lds16(pB + 64 * (size_t)KK + ko_,     &ldsB[nb][(1 * 512 + tid) * 8]); \
    gld_lds16(pB + 128 * (size_t)KK + ko_,    &ldsB[nb][(2 * 512 + tid) * 8]); \
    gld_lds16(pB + 192 * (size_t)KK + ko_,    &ldsB[nb][(3 * 512 + tid) * 8]); \
} while (0)

#define CLUSTER(MH, NH) do {                                                   \
    __builtin_amdgcn_s_setprio(1);                                             \
    _Pragma("unroll")                                                          \
    for (int mi = 0; mi < 4; mi++) {                                           \
        _Pragma("unroll")                                                      \
        for (int gg = 0; gg < 2; gg++) {                                       \
            const int g = (NH) * 2 + gg;                                       \
            acc[(MH) * 4 + mi][g] = __builtin_amdgcn_mfma_f32_16x16x32_bf16(   \
                af[mi][0], bfr[g][0], acc[(MH) * 4 + mi][g], 0, 0, 0);         \
            acc[(MH) * 4 + mi][g] = __builtin_amdgcn_mfma_f32_16x16x32_bf16(   \
                af[mi][1], bfr[g][1], acc[(MH) * 4 + mi][g], 0, 0, 0);         \
        }                                                                      \
    }                                                                          \
    __builtin_amdgcn_s_setprio(0);                                             \
} while (0)

    // prologue: tile 0 fully staged; queue = [0.A4, 0.B4]
    STAGE_A(0, 0);
    STAGE_B(0, 0);

#pragma unroll 2
    for (int T = 0; T < 16; ++T) {
        const int cur = T & 1;
        // entry: issue next A; counted wait lands tile T (A+B), keeps T+1.A.
        if (T < 15) {
            STAGE_A(T + 1, cur ^ 1);
            asm volatile("s_waitcnt vmcnt(4)" ::: "memory");
        } else {
            asm volatile("s_waitcnt vmcnt(0)" ::: "memory");
        }
        __builtin_amdgcn_s_barrier();
        __builtin_amdgcn_sched_barrier(0);  // reads must not hoist above barrier

        bf16x8 af[4][2], bfr[4][2];
#pragma unroll
        for (int g = 0; g < 4; g++) {
            bfr[g][0] = *(const bf16x8*)&ldsB[cur][bb + (g * 16) * 64 + u0];
            bfr[g][1] = *(const bf16x8*)&ldsB[cur][bb + (g * 16) * 64 + u1];
        }
#pragma unroll
        for (int mi = 0; mi < 4; mi++) {
            af[mi][0] = *(const bf16x8*)&ldsA[cur][ab + (mi * 16) * 64 + u0];
            af[mi][1] = *(const bf16x8*)&ldsA[cur][ab + (mi * 16) * 64 + u1];
        }

        CLUSTER(0, 0);
        __builtin_amdgcn_s_barrier();
        CLUSTER(0, 1);
        __builtin_amdgcn_s_barrier();

        // reload af for M-half 1; issue next B under this half's MFMA
#pragma unroll
        for (int mi = 0; mi < 4; mi++) {
            af[mi][0] = *(const bf16x8*)&ldsA[cur][ab + (64 + mi * 16) * 64 + u0];
            af[mi][1] = *(const bf16x8*)&ldsA[cur][ab + (64 + mi * 16) * 64 + u1];
        }
        if (T < 15) STAGE_B(T + 1, cur ^ 1);
        __builtin_amdgcn_s_barrier();

        CLUSTER(1, 0);
        __builtin_amdgcn_s_barrier();
        CLUSTER(1, 1);
        __builtin_amdgcn_s_barrier();
    }
#undef STAGE_A
#undef STAGE_B
#undef CLUSTER

    // epilogue: lane owns gates i,f,o,g (g=0..3) at h fixed per lane
    float bi[4];
#pragma unroll
    for (int g = 0; g < 4; g++)
        bi[g] = biasc[n0 + wn * 64 + g * 16 + lrow];
    const int h = (bn * 4 + wn) * 16 + lrow;

#pragma unroll
    for (int mi = 0; mi < 8; mi++) {
#pragma unroll
        for (int r = 0; r < 4; r++) {
            int b = m0 + wm * 128 + mi * 16 + quad * 4 + r;
            float zi = acc[mi][0][r] + bi[0];
            float zf = acc[mi][1][r] + bi[1];
            float zo = acc[mi][2][r] + bi[2];
            float zg = acc[mi][3][r] + bi[3];
            float ig = 1.f / (1.f + __expf(-zi));
            float fg = 1.f / (1.f + __expf(-zf));
            float og = 1.f / (1.f + __expf(-zo));
            float gg = 1.f - 2.f / (__expf(2.f * zg) + 1.f);  // tanh, stable
            float c0v = c0[(size_t)b * HQ + h];
            float c1 = fg * c0v + ig * gg;
            float th = 1.f - 2.f / (__expf(2.f * c1) + 1.f);
            out[(size_t)b * HQ + h] = og * th;                 // h1
            out[(size_t)BH + (size_t)b * HQ + h] = c1;         // c1
        }
    }
}

extern "C" void kernel_launch(void* const* d_in, const int* in_sizes, int n_in,
                              void* d_out, int out_size, void* d_ws, size_t ws_size,
                              hipStream_t stream) {
    (void)in_sizes; (void)n_in; (void)out_size; (void)ws_size;
    const float* input = (const float*)d_in[0];
    const float* h0    = (const float*)d_in[1];
    const float* c0    = (const float*)d_in[2];
    const float* Wx    = (const float*)d_in[3];
    const float* bx    = (const float*)d_in[4];
    const float* Wh    = (const float*)d_in[5];
    const float* bh    = (const float*)d_in[6];
    float* out = (float*)d_out;

    char* ws = (char*)d_ws;
    unsigned short* Xcat = (unsigned short*)ws;                      // 64 MiB
    unsigned short* Wint = (unsigned short*)(ws + (size_t)67108864); // 4 MiB
    float* biasc = (float*)(ws + (size_t)71303168);                  // 8 KiB

    pack_X<<<32768, 256, 0, stream>>>(input, h0, Xcat);
    pack_W<<<2048, 256, 0, stream>>>(Wx, Wh, bx, bh, Wint, biasc);
    lstm_gemm<<<1024, 512, 0, stream>>>(Xcat, Wint, biasc, c0, out);
}

// Round 5
// 418.885 us; speedup vs baseline: 1.2998x; 1.0206x over previous
//
#include <hip/hip_runtime.h>

// LSTM cell fused as one GEMM: Z[B,2048] = [input|h0] (bf16) @ Wint^T (bf16)
// Wint column order c: h_group = c>>6, gate = (c>>4)&3, h_low = c&15
//   => each wave's four 16-col MFMA subtiles are gates i,f,o,g at the SAME h,
//      so the gate nonlinearity fuses into the epilogue lane-locally.
//
// Round-5 structure: TLP over lockstep. BM=256 x BN=128, BK=32, 512 thr =
// 8 waves (4M x 2N), wave tile 64x64 (acc[4][4] = 64 regs). LDS = 3 bufs x
// (A 16K + B 8K) = 72 KiB -> 2 blocks/CU (144 KiB), 16 waves/CU; enforced
// via __launch_bounds__(512,4) (combined regs <= 128). Pipeline lead = 2
// tiles: at iter T stage T+2 (3 gld_lds/thread), ONE s_waitcnt vmcnt(6)
// (leaves tiles T+1,T+2 in flight), 2 barriers/tile. The second resident
// block fills every stall (m114-style implicit overlap).
// Swizzle (measured 0 conflicts in r4, re-derived for 32-elem rows):
// source unit (t&3)^((t>>3)&3), read unit quad^((lrow>>1)&3) -> <=2-way.
// B=32768, E=H=512, K=1024, N=2048.

#define BQ 32768
#define HQ 512
#define KK 1024
#define BH (32768 * 512)  // elements per output

typedef __bf16 bf16x8 __attribute__((ext_vector_type(8)));
typedef float f32x4 __attribute__((ext_vector_type(4)));

__device__ __forceinline__ unsigned short f2bf(float f) {
    unsigned int u = __float_as_uint(f);
    unsigned int r = (u + 0x7fffu + ((u >> 16) & 1u)) >> 16;
    return (unsigned short)r;
}

__device__ __forceinline__ void gld_lds16(const unsigned short* g, unsigned short* l) {
    __builtin_amdgcn_global_load_lds(
        (const __attribute__((address_space(1))) void*)g,
        (__attribute__((address_space(3))) void*)l,
        16, 0, 0);
}

// ---- prepass: fp32 -> bf16 packing -----------------------------------------

__global__ __launch_bounds__(256) void pack_X(const float* __restrict__ in,
                                              const float* __restrict__ h0,
                                              unsigned short* __restrict__ Xcat) {
    const int NQ = BQ * HQ / 4;
    int gi = blockIdx.x * 256 + threadIdx.x;
    const float* src;
    size_t dst;
    if (gi < NQ) {
        int e = gi * 4;
        int b = e >> 9, col = e & 511;
        src = in + e;
        dst = (size_t)b * 1024 + col;
    } else {
        int e = (gi - NQ) * 4;
        int b = e >> 9, col = e & 511;
        src = h0 + e;
        dst = (size_t)b * 1024 + 512 + col;
    }
    float4 v = *(const float4*)src;
    ushort4 o;
    o.x = f2bf(v.x); o.y = f2bf(v.y); o.z = f2bf(v.z); o.w = f2bf(v.w);
    *(ushort4*)&Xcat[dst] = o;
}

__global__ __launch_bounds__(256) void pack_W(const float* __restrict__ Wx,
                                              const float* __restrict__ Wh,
                                              const float* __restrict__ bx,
                                              const float* __restrict__ bh,
                                              unsigned short* __restrict__ Wint,
                                              float* __restrict__ biasc) {
    int j = blockIdx.x * 256 + threadIdx.x;
    int c = j >> 8;
    int kc = (j & 255) * 4;
    int gate = (c >> 4) & 3;
    int h = ((c >> 6) << 4) + (c & 15);
    const float* src = (kc < 512)
        ? (Wx + ((size_t)gate * 512 + h) * 512 + kc)
        : (Wh + ((size_t)gate * 512 + h) * 512 + (kc - 512));
    float4 v = *(const float4*)src;
    ushort4 o;
    o.x = f2bf(v.x); o.y = f2bf(v.y); o.z = f2bf(v.z); o.w = f2bf(v.w);
    *(ushort4*)&Wint[(size_t)c * 1024 + kc] = o;
    if ((j & 255) == 0) biasc[c] = bx[gate * 512 + h] + bh[gate * 512 + h];
}

// ---- fused GEMM + LSTM epilogue --------------------------------------------

__global__ __launch_bounds__(512, 4) void lstm_gemm(const unsigned short* __restrict__ Xcat,
                                                    const unsigned short* __restrict__ Wint,
                                                    const float* __restrict__ biasc,
                                                    const float* __restrict__ c0,
                                                    float* __restrict__ out) {
    __shared__ __align__(16) unsigned short ldsA[3][256 * 32];  // 48 KiB
    __shared__ __align__(16) unsigned short ldsB[3][128 * 32];  // 24 KiB

    const int tid = threadIdx.x;
    const int lane = tid & 63;
    const int wave = tid >> 6;     // 0..7
    const int wm = wave >> 1;      // 0..3 (M)
    const int wn = wave & 1;       // 0..1 (N) = h_group within block
    const int quad = lane >> 4;    // 0..3
    const int lrow = lane & 15;    // 0..15

    // XCD-chunked swizzle (2048 % 8 == 0 -> bijective): each XCD owns
    // 16 consecutive bm x all 16 bn -> A-panel shared within one XCD's L2.
    const int bid = blockIdx.x;
    const int l = bid >> 3;
    const int bm = (bid & 7) * 16 + (l >> 4);  // 0..127
    const int bn = l & 15;                     // 0..15
    const int m0 = bm * 256;
    const int n0 = bn * 128;

    // staging: thread t = one 16B unit; row t>>2 (0..127), unit (t&3),
    // source column unit swizzled by (row>>1)&3 = (t>>3)&3.
    const int srow = tid >> 2;
    const int scol = ((tid & 3) ^ ((tid >> 3) & 3)) * 8;
    const unsigned short* pA  = Xcat + (size_t)(m0 + srow) * KK + scol;  // rows 0..127
    const unsigned short* pA2 = pA + (size_t)128 * KK;                   // rows 128..255
    const unsigned short* pB  = Wint + (size_t)(n0 + srow) * KK + scol;  // rows 0..127

    // read-side: phys unit = quad ^ ((lrow>>1)&3)  (row>>1 &3 == lrow>>1 &3
    // since all row bases are multiples of 16)
    const int koff = (quad ^ ((lrow >> 1) & 3)) * 8;
    const int ar = (wm * 64 + lrow) * 32 + koff;   // + mi*512
    const int br = (wn * 64 + lrow) * 32 + koff;   // + g*512

    f32x4 acc[4][4];
#pragma unroll
    for (int i = 0; i < 4; i++)
#pragma unroll
        for (int j = 0; j < 4; j++) {
            f32x4 z = {0.f, 0.f, 0.f, 0.f};
            acc[i][j] = z;
        }

#define STAGE(Tt, W) do { const int ko_ = (Tt) * 32;                           \
    gld_lds16(pA  + ko_, &ldsA[W][tid * 8]);                                   \
    gld_lds16(pA2 + ko_, &ldsA[W][4096 + tid * 8]);                            \
    gld_lds16(pB  + ko_, &ldsB[W][tid * 8]);                                   \
} while (0)

#define COMPUTE(R) do {                                                        \
    bf16x8 af[4], bfr[4];                                                      \
    _Pragma("unroll")                                                          \
    for (int mi = 0; mi < 4; mi++)                                             \
        af[mi] = *(const bf16x8*)&ldsA[R][ar + mi * 512];                      \
    _Pragma("unroll")                                                          \
    for (int g = 0; g < 4; g++)                                                \
        bfr[g] = *(const bf16x8*)&ldsB[R][br + g * 512];                       \
    __builtin_amdgcn_s_setprio(1);                                             \
    _Pragma("unroll")                                                          \
    for (int mi = 0; mi < 4; mi++)                                             \
        _Pragma("unroll")                                                      \
        for (int g = 0; g < 4; g++)                                            \
            acc[mi][g] = __builtin_amdgcn_mfma_f32_16x16x32_bf16(              \
                af[mi], bfr[g], acc[mi][g], 0, 0, 0);                          \
    __builtin_amdgcn_s_setprio(0);                                             \
} while (0)

// iter T: stage T+2 into W=(T+2)%3; vmcnt(6) = tiles T+1,T+2 in flight,
// tile T landed; barrier; read R=T%3; MFMA; barrier (protects R from the
// STAGE(T+3 -> R) issued at iter T+1).
#define ITER(Tt, R, W) do {                                                    \
    STAGE((Tt) + 2, W);                                                        \
    asm volatile("s_waitcnt vmcnt(6)" ::: "memory");                           \
    __builtin_amdgcn_s_barrier();                                              \
    __builtin_amdgcn_sched_barrier(0);                                         \
    COMPUTE(R);                                                                \
    __builtin_amdgcn_s_barrier();                                              \
} while (0)

    // prologue: tiles 0,1 staged to bufs 0,1
    STAGE(0, 0);
    STAGE(1, 1);

    for (int T = 0; T < 30; T += 3) {
        ITER(T + 0, 0, 2);
        ITER(T + 1, 1, 0);
        ITER(T + 2, 2, 1);
    }
    // T=30: no stage; only tile31's 3 loads outstanding
    asm volatile("s_waitcnt vmcnt(3)" ::: "memory");
    __builtin_amdgcn_s_barrier();
    __builtin_amdgcn_sched_barrier(0);
    COMPUTE(0);
    // T=31
    asm volatile("s_waitcnt vmcnt(0)" ::: "memory");
    __builtin_amdgcn_s_barrier();
    __builtin_amdgcn_sched_barrier(0);
    COMPUTE(1);

#undef ITER
#undef COMPUTE
#undef STAGE

    // epilogue: lane owns gates i,f,o,g (g=0..3) at h fixed per lane
    float bi[4];
#pragma unroll
    for (int g = 0; g < 4; g++)
        bi[g] = biasc[n0 + wn * 64 + g * 16 + lrow];
    const int h = (bn * 2 + wn) * 16 + lrow;

#pragma unroll
    for (int mi = 0; mi < 4; mi++) {
#pragma unroll
        for (int r = 0; r < 4; r++) {
            int b = m0 + wm * 64 + mi * 16 + quad * 4 + r;
            float zi = acc[mi][0][r] + bi[0];
            float zf = acc[mi][1][r] + bi[1];
            float zo = acc[mi][2][r] + bi[2];
            float zg = acc[mi][3][r] + bi[3];
            float ig = 1.f / (1.f + __expf(-zi));
            float fg = 1.f / (1.f + __expf(-zf));
            float og = 1.f / (1.f + __expf(-zo));
            float gg = 1.f - 2.f / (__expf(2.f * zg) + 1.f);  // tanh, stable
            float c0v = c0[(size_t)b * HQ + h];
            float c1 = fg * c0v + ig * gg;
            float th = 1.f - 2.f / (__expf(2.f * c1) + 1.f);
            out[(size_t)b * HQ + h] = og * th;                 // h1
            out[(size_t)BH + (size_t)b * HQ + h] = c1;         // c1
        }
    }
}

extern "C" void kernel_launch(void* const* d_in, const int* in_sizes, int n_in,
                              void* d_out, int out_size, void* d_ws, size_t ws_size,
                              hipStream_t stream) {
    (void)in_sizes; (void)n_in; (void)out_size; (void)ws_size;
    const float* input = (const float*)d_in[0];
    const float* h0    = (const float*)d_in[1];
    const float* c0    = (const float*)d_in[2];
    const float* Wx    = (const float*)d_in[3];
    const float* bx    = (const float*)d_in[4];
    const float* Wh    = (const float*)d_in[5];
    const float* bh    = (const float*)d_in[6];
    float* out = (float*)d_out;

    char* ws = (char*)d_ws;
    unsigned short* Xcat = (unsigned short*)ws;                      // 64 MiB
    unsigned short* Wint = (unsigned short*)(ws + (size_t)67108864); // 4 MiB
    float* biasc = (float*)(ws + (size_t)71303168);                  // 8 KiB

    pack_X<<<32768, 256, 0, stream>>>(input, h0, Xcat);
    pack_W<<<2048, 256, 0, stream>>>(Wx, Wh, bx, bh, Wint, biasc);
    lstm_gemm<<<2048, 512, 0, stream>>>(Xcat, Wint, biasc, c0, out);
}